// Round 2
// 269.440 us; speedup vs baseline: 1.0206x; 1.0206x over previous
//
#include <hip/hip_runtime.h>

#define BATCH 4096
#define IN_F 8192
#define OUT_F 8192
#define NG 1024
#define NW (NG * IN_F)
#define RCHUNKS 256        // row chunks of 16 rows each
#define ROWS_PER_BLK 16    // 16 fully-unrolled float4 loads/thread -> high MLP

typedef float f4raw __attribute__((ext_vector_type(4)));  // native vec for nontemporal builtin

// ws layout (floats): part[RCHUNKS * IN_F] (8 MB) | spart[32] | flag(int)
// No memset needed: every word we read is plain-stored by an earlier kernel.
//
// NUMERICS: absmax vs reference is exactly 0.0 with this reduction structure.
// Do NOT change any FP accumulation order: 16-row chunk partials, sequential
// y=0..255 csum chain, 256-wide LDS tree, K3's paren order for s.

// K1: per-rowchunk column partial sums of x (4096 x 8192 row-major)
//     + streaming zero-fill of out rows 1..4095 (no dependency on anything,
//       so it overlaps the x reads instead of sitting serially after K2).
// grid (8, 256): 2048 blocks; plain float4 stores, no atomics.
__global__ __launch_bounds__(256) void colsum_zero_kernel(const float* __restrict__ x,
                                                          float4* __restrict__ part4,
                                                          float4* __restrict__ out4) {
    const int col4 = blockIdx.x * 256 + threadIdx.x;              // 0..2047
    const int y = blockIdx.y;                                     // row chunk
    const float4* __restrict__ xp = (const float4*)x;
    const int stride4 = IN_F / 4;
    long long base = (long long)(y * ROWS_PER_BLK) * stride4 + col4;
    float4 v[ROWS_PER_BLK];
#pragma unroll
    for (int r = 0; r < ROWS_PER_BLK; ++r)
        v[r] = xp[base + (long long)r * stride4];

    // Zero-fill out float4 indices [2048, 8388608) — rows 1..4095.
    // 524288 threads x 16 stores covers it (last iteration guarded).
    // Nontemporal: streaming, written-once, never re-read this iteration.
    {
        const long long lin = ((long long)blockIdx.y * gridDim.x + blockIdx.x) * 256
                            + threadIdx.x;                        // 0..524287
        const long long nthreads = 524288;
        const f4raw z = (f4raw){0.f, 0.f, 0.f, 0.f};
        f4raw* __restrict__ outr = (f4raw*)out4;
#pragma unroll
        for (int k = 0; k < 16; ++k) {
            long long idx = (long long)(OUT_F / 4) + lin + (long long)k * nthreads;
            if (idx < (long long)BATCH * OUT_F / 4)
                __builtin_nontemporal_store(z, &outr[idx]);
        }
    }

    float a0 = 0.f, a1 = 0.f, a2 = 0.f, a3 = 0.f;
#pragma unroll
    for (int r = 0; r < ROWS_PER_BLK; ++r) {
        a0 += v[r].x; a1 += v[r].y; a2 += v[r].z; a3 += v[r].w;
    }
    part4[(long long)y * stride4 + col4] = make_float4(a0, a1, a2, a3);
}

// K2: 32 blocks x 256 threads, one column each. Reduce the 256 partials per
// column (64-deep load batches for MLP — add order is the same serial chain,
// bit-identical), then searchsorted(mins,val,'right')-1 on LDS tables, gather
// weight, block-reduce, plain-store spart[block]. Block 0 also detects the
// out_mask storage layout (int32 vs 1-byte bool) and plain-stores the flag.
__global__ __launch_bounds__(256) void scalar_kernel(const float* __restrict__ part,
                                                     const float* __restrict__ mins,
                                                     const float* __restrict__ maxs,
                                                     const int* __restrict__ start_pos,
                                                     const int* __restrict__ offsets,
                                                     const int* __restrict__ sizes,
                                                     const float* __restrict__ wflat,
                                                     const unsigned char* __restrict__ mask_raw,
                                                     float* __restrict__ spart,
                                                     int* __restrict__ flag) {
    __shared__ float smins[NG];
    __shared__ int sstart[NG];
    __shared__ int soffs[NG];
    __shared__ int ssize[NG];
    __shared__ float sred[256];
    const int t = threadIdx.x;
    for (int i = t; i < NG; i += 256) {
        smins[i]  = mins[i];
        sstart[i] = start_pos[i];
        soffs[i]  = offsets[i];
        ssize[i]  = sizes[i];
    }
    __syncthreads();

    const int j = blockIdx.x * 256 + t;       // 32*256 == IN_F exactly
    float csum = 0.f;
    const float* __restrict__ pj = part + j;
#pragma unroll 1
    for (int y0 = 0; y0 < RCHUNKS; y0 += 64) {
        float v[64];
#pragma unroll
        for (int i = 0; i < 64; ++i)
            v[i] = pj[(long long)(y0 + i) * IN_F];   // 64 independent loads in flight
#pragma unroll
        for (int i = 0; i < 64; ++i)
            csum += v[i];                            // same serial add chain as before
    }
    float val = csum * (1.0f / (float)BATCH);

    // searchsorted right: first index with mins[idx] > val
    int lo = 0, hi = NG;
    while (lo < hi) {
        int mid = (lo + hi) >> 1;
        if (smins[mid] <= val) lo = mid + 1; else hi = mid;
    }
    int g = lo - 1;
    float local = 0.f;
    if (g >= 0 && val >= smins[g] && val <= maxs[g]) {
        int pos = j - sstart[g];
        if (pos >= 0 && pos < ssize[g]) {
            long long idx = (long long)soffs[g] + (long long)pos;
            if (idx < 0) idx = 0;
            if (idx > (long long)(NW - 1)) idx = NW - 1;
            local = val * wflat[idx];
        }
    }
    sred[t] = local;
    __syncthreads();
    for (int ofs = 128; ofs > 0; ofs >>= 1) {
        if (t < ofs) sred[t] += sred[t + ofs];
        __syncthreads();
    }
    if (t == 0) spart[blockIdx.x] = sred[0];

    // mask layout detection (block 0): first 8192 bytes as 2048 int32.
    // int32 0/1 layout -> every word in {0,1}; packed bools -> words like 0x01000101.
    if (blockIdx.x == 0) {
        const int* mi = (const int*)mask_raw;
        int ok = 1;
#pragma unroll
        for (int i = 0; i < 8; ++i) {
            int v = mi[t * 8 + i];
            ok &= (v == 0 || v == 1) ? 1 : 0;
        }
        __shared__ int sflag[256];
        sflag[t] = ok;
        __syncthreads();
        for (int ofs = 128; ofs > 0; ofs >>= 1) {
            if (t < ofs) sflag[t] &= sflag[t + ofs];
            __syncthreads();
        }
        if (t == 0) *flag = sflag[0];         // 1 => int32 layout
    }
}

// K3: row 0 only (32 KB): mask ? s : 0. Rows 1..4095 were zeroed in K1.
// Threads reconstruct s from the 32 block partials (L2-broadcast reads)
// with the EXACT same paren order as the previous verified kernel.
__global__ __launch_bounds__(256) void row0_kernel(const unsigned char* __restrict__ mask_raw,
                                                   const float* __restrict__ spart,
                                                   const int* __restrict__ flag,
                                                   float4* __restrict__ out4) {
    const int i = blockIdx.x * 256 + threadIdx.x;   // 0..2047 == OUT_F/4
    const float4* sp4 = (const float4*)spart;
    float4 p0 = sp4[0], p1 = sp4[1], p2 = sp4[2], p3 = sp4[3];
    float4 p4 = sp4[4], p5 = sp4[5], p6 = sp4[6], p7 = sp4[7];
    float s = ((p0.x + p0.y + p0.z + p0.w) + (p1.x + p1.y + p1.z + p1.w))
            + ((p2.x + p2.y + p2.z + p2.w) + (p3.x + p3.y + p3.z + p3.w))
            + ((p4.x + p4.y + p4.z + p4.w) + (p5.x + p5.y + p5.z + p5.w))
            + ((p6.x + p6.y + p6.z + p6.w) + (p7.x + p7.y + p7.z + p7.w));
    const int mask_is_i32 = *flag;
    const int j = i * 4;
    int m0, m1, m2, m3;
    if (mask_is_i32) {
        const int* mi = (const int*)mask_raw;
        m0 = mi[j]; m1 = mi[j + 1]; m2 = mi[j + 2]; m3 = mi[j + 3];
    } else {
        m0 = mask_raw[j]; m1 = mask_raw[j + 1];
        m2 = mask_raw[j + 2]; m3 = mask_raw[j + 3];
    }
    float4 v = make_float4(m0 ? s : 0.f, m1 ? s : 0.f, m2 ? s : 0.f, m3 ? s : 0.f);
    out4[i] = v;
}

extern "C" void kernel_launch(void* const* d_in, const int* in_sizes, int n_in,
                              void* d_out, int out_size, void* d_ws, size_t ws_size,
                              hipStream_t stream) {
    const float* x          = (const float*)d_in[0];
    const float* wflat      = (const float*)d_in[1];
    const float* mins       = (const float*)d_in[2];
    const float* maxs       = (const float*)d_in[3];
    const int*   start_pos  = (const int*)d_in[4];
    const int*   offsets    = (const int*)d_in[5];
    const int*   sizes      = (const int*)d_in[6];
    const unsigned char* mask = (const unsigned char*)d_in[7];

    float* part   = (float*)d_ws;                       // RCHUNKS*IN_F floats (8 MB)
    float* spart  = part + (long long)RCHUNKS * IN_F;   // 32 floats
    int*   flag   = (int*)(spart + 32);                 // 1 int

    colsum_zero_kernel<<<dim3(IN_F / (256 * 4), RCHUNKS), 256, 0, stream>>>(
        x, (float4*)part, (float4*)d_out);
    scalar_kernel<<<IN_F / 256, 256, 0, stream>>>(part, mins, maxs, start_pos, offsets,
                                                  sizes, wflat, mask, spart, flag);
    row0_kernel<<<OUT_F / (256 * 4), 256, 0, stream>>>(mask, spart, flag, (float4*)d_out);
}